// Round 1
// baseline (2094.334 us; speedup 1.0000x reference)
//
#include <hip/hip_runtime.h>
#include <math.h>

#define HID   1024
#define STT   4096
#define MTOK  4096   // B*L
#define LSEQ  2048
#define BATCH 2
#define NCHUNK 32
#define CHUNK  64    // LSEQ/NCHUNK
#define VOCAB  62

#define BM 64
#define BN 64
#define BK 16

__device__ __forceinline__ float sigmoidf_(float x) {
    return 1.0f / (1.0f + expf(-x));
}

// ---------------- Kernel 1: embedding gather + RMSNorm ----------------
__global__ __launch_bounds__(256) void embed_norm_kernel(
    const int* __restrict__ tokens, const float* __restrict__ embed_w,
    const float* __restrict__ norm_w, float* __restrict__ xn)
{
    int m = blockIdx.x;            // token index
    int t = threadIdx.x;           // 0..255, each owns 4 contiguous floats
    int tok = tokens[m];
    const float4* row = (const float4*)(embed_w + (size_t)tok * HID);
    float4 x = row[t];
    float ss = x.x * x.x + x.y * x.y + x.z * x.z + x.w * x.w;
    // wave (64-lane) reduce, then cross-wave via LDS
    for (int off = 32; off > 0; off >>= 1) ss += __shfl_down(ss, off);
    __shared__ float wsum[4];
    if ((t & 63) == 0) wsum[t >> 6] = ss;
    __syncthreads();
    float tot = wsum[0] + wsum[1] + wsum[2] + wsum[3];
    float scale = rsqrtf(tot / (float)HID + 1e-6f);
    const float4* nw = (const float4*)norm_w;
    float4 w4 = nw[t];
    float4 o;
    o.x = x.x * scale * w4.x; o.y = x.y * scale * w4.y;
    o.z = x.z * scale * w4.z; o.w = x.w * scale * w4.w;
    ((float4*)(xn + (size_t)m * HID))[t] = o;
}

// ---------------- Kernel 2: fused input GEMM + gates ----------------
// proj[m, g*S+n] = sum_k xn[m,k]*in_w[k, g*S+n] + in_b[g*S+n]
// a = sig(proj_g1); bx = sig(proj_g2)*proj_g0; c = sig(proj_g3)
__global__ __launch_bounds__(256) void gemm_in_kernel(
    const float* __restrict__ xn, const float* __restrict__ in_w,
    const float* __restrict__ in_b,
    float* __restrict__ a_buf, float* __restrict__ bx_buf, float* __restrict__ c_buf)
{
    __shared__ float As[BK][BM];        // [k][m]
    __shared__ float Bs[4][BK][BN];     // [g][k][n]
    int tid = threadIdx.x;
    int tx = tid & 15, ty = tid >> 4;
    int m0 = blockIdx.y * BM;
    int n0 = blockIdx.x * BN;
    float acc[4][4][4];
    #pragma unroll
    for (int g = 0; g < 4; g++)
        #pragma unroll
        for (int i = 0; i < 4; i++)
            #pragma unroll
            for (int j = 0; j < 4; j++) acc[g][i][j] = 0.f;

    int rowA = tid >> 2, kqA = (tid & 3) << 2;      // A-load mapping
    int kb = tid >> 4, nq = (tid & 15) << 2;        // B-load mapping

    for (int k0 = 0; k0 < HID; k0 += BK) {
        float4 av = *(const float4*)(xn + (size_t)(m0 + rowA) * HID + k0 + kqA);
        As[kqA + 0][rowA] = av.x; As[kqA + 1][rowA] = av.y;
        As[kqA + 2][rowA] = av.z; As[kqA + 3][rowA] = av.w;
        #pragma unroll
        for (int g = 0; g < 4; g++) {
            float4 bv = *(const float4*)(in_w + (size_t)(k0 + kb) * (4 * STT) + g * STT + n0 + nq);
            *(float4*)&Bs[g][kb][nq] = bv;
        }
        __syncthreads();
        #pragma unroll
        for (int kk = 0; kk < BK; kk++) {
            float4 av4 = *(const float4*)&As[kk][ty << 2];
            float a4[4] = {av4.x, av4.y, av4.z, av4.w};
            #pragma unroll
            for (int g = 0; g < 4; g++) {
                float4 bv4 = *(const float4*)&Bs[g][kk][tx << 2];
                float b4[4] = {bv4.x, bv4.y, bv4.z, bv4.w};
                #pragma unroll
                for (int i = 0; i < 4; i++)
                    #pragma unroll
                    for (int j = 0; j < 4; j++)
                        acc[g][i][j] = fmaf(a4[i], b4[j], acc[g][i][j]);
            }
        }
        __syncthreads();
    }
    // epilogue: gates
    #pragma unroll
    for (int i = 0; i < 4; i++) {
        int m = m0 + (ty << 2) + i;
        int nb = n0 + (tx << 2);
        float o_a[4], o_bx[4], o_c[4];
        #pragma unroll
        for (int j = 0; j < 4; j++) {
            int n = nb + j;
            float vx = acc[0][i][j] + in_b[0 * STT + n];
            float va = acc[1][i][j] + in_b[1 * STT + n];
            float vb = acc[2][i][j] + in_b[2 * STT + n];
            float vc = acc[3][i][j] + in_b[3 * STT + n];
            o_a[j]  = sigmoidf_(va);
            o_bx[j] = sigmoidf_(vb) * vx;
            o_c[j]  = sigmoidf_(vc);
        }
        *(float4*)(a_buf  + (size_t)m * STT + nb) = make_float4(o_a[0],  o_a[1],  o_a[2],  o_a[3]);
        *(float4*)(bx_buf + (size_t)m * STT + nb) = make_float4(o_bx[0], o_bx[1], o_bx[2], o_bx[3]);
        *(float4*)(c_buf  + (size_t)m * STT + nb) = make_float4(o_c[0],  o_c[1],  o_c[2],  o_c[3]);
    }
}

// ---------------- Kernels 3-5: chunked linear-recurrence scan ----------------
// channel = (b, s); h_t = a_t*h_{t-1} + bx_t
__global__ __launch_bounds__(256) void scan_phase1(
    const float* __restrict__ a_buf, const float* __restrict__ bx_buf,
    float* __restrict__ chunkA, float* __restrict__ chunkH)
{
    int bid = blockIdx.x;                  // 1024 blocks: 16 sgrp x 32 q x 2 b
    int sg = bid & 15, q = (bid >> 4) & 31, b = bid >> 9;
    int s = sg * 256 + threadIdx.x;
    int t0 = q * CHUNK;
    float A = 1.f, Hh = 0.f;
    const float* ap = a_buf  + (size_t)(b * LSEQ + t0) * STT + s;
    const float* bp = bx_buf + (size_t)(b * LSEQ + t0) * STT + s;
    for (int t = 0; t < CHUNK; t++) {
        float av = ap[(size_t)t * STT];
        float bv = bp[(size_t)t * STT];
        Hh = fmaf(av, Hh, bv);
        A *= av;
    }
    int ch = b * STT + s;
    chunkA[ch * NCHUNK + q] = A;
    chunkH[ch * NCHUNK + q] = Hh;
}

__global__ __launch_bounds__(256) void scan_phase2(
    const float* __restrict__ chunkA, const float* __restrict__ chunkH,
    float* __restrict__ carry)
{
    int ch = blockIdx.x * 256 + threadIdx.x;   // 8192 channels
    float c = 0.f;
    for (int q = 0; q < NCHUNK; q++) {
        carry[ch * NCHUNK + q] = c;
        c = fmaf(chunkA[ch * NCHUNK + q], c, chunkH[ch * NCHUNK + q]);
    }
}

// phase3: recompute h with carry-in, write y = c_gate * h over a_buf
__global__ __launch_bounds__(256) void scan_phase3(
    float* __restrict__ a_buf, const float* __restrict__ bx_buf,
    const float* __restrict__ c_buf, const float* __restrict__ carry)
{
    int bid = blockIdx.x;
    int sg = bid & 15, q = (bid >> 4) & 31, b = bid >> 9;
    int s = sg * 256 + threadIdx.x;
    int t0 = q * CHUNK;
    int ch = b * STT + s;
    float h = carry[ch * NCHUNK + q];
    for (int t = 0; t < CHUNK; t++) {
        size_t idx = (size_t)(b * LSEQ + t0 + t) * STT + s;
        float av = a_buf[idx], bv = bx_buf[idx];
        h = fmaf(av, h, bv);
        a_buf[idx] = c_buf[idx] * h;    // y
    }
}

// ---------------- Kernel 6: output GEMM + bias + residual ----------------
// out[m,n] = sum_k y[m,k]*out_w[k,n] + out_b[n] + embed_w[tok[m], n]
__global__ __launch_bounds__(256) void gemm_out_kernel(
    const float* __restrict__ y, const float* __restrict__ out_w,
    const float* __restrict__ out_b, const int* __restrict__ tokens,
    const float* __restrict__ embed_w, float* __restrict__ outbuf)
{
    __shared__ float As[BK][BM];
    __shared__ float Bs[BK][BN];
    int tid = threadIdx.x;
    int tx = tid & 15, ty = tid >> 4;
    int m0 = blockIdx.y * BM;
    int n0 = blockIdx.x * BN;
    float acc[4][4];
    #pragma unroll
    for (int i = 0; i < 4; i++)
        #pragma unroll
        for (int j = 0; j < 4; j++) acc[i][j] = 0.f;

    int rowA = tid >> 2, kqA = (tid & 3) << 2;
    int kb = tid >> 4, nq = (tid & 15) << 2;

    for (int k0 = 0; k0 < STT; k0 += BK) {
        float4 av = *(const float4*)(y + (size_t)(m0 + rowA) * STT + k0 + kqA);
        As[kqA + 0][rowA] = av.x; As[kqA + 1][rowA] = av.y;
        As[kqA + 2][rowA] = av.z; As[kqA + 3][rowA] = av.w;
        float4 bv = *(const float4*)(out_w + (size_t)(k0 + kb) * HID + n0 + nq);
        *(float4*)&Bs[kb][nq] = bv;
        __syncthreads();
        #pragma unroll
        for (int kk = 0; kk < BK; kk++) {
            float4 av4 = *(const float4*)&As[kk][ty << 2];
            float a4[4] = {av4.x, av4.y, av4.z, av4.w};
            float4 bv4 = *(const float4*)&Bs[kk][tx << 2];
            float b4[4] = {bv4.x, bv4.y, bv4.z, bv4.w};
            #pragma unroll
            for (int i = 0; i < 4; i++)
                #pragma unroll
                for (int j = 0; j < 4; j++)
                    acc[i][j] = fmaf(a4[i], b4[j], acc[i][j]);
        }
        __syncthreads();
    }
    #pragma unroll
    for (int i = 0; i < 4; i++) {
        int m = m0 + (ty << 2) + i;
        int nb = n0 + (tx << 2);
        int tok = tokens[m];
        float4 r4 = *(const float4*)(embed_w + (size_t)tok * HID + nb);
        float4 b4 = *(const float4*)(out_b + nb);
        float4 o;
        o.x = acc[i][0] + b4.x + r4.x;
        o.y = acc[i][1] + b4.y + r4.y;
        o.z = acc[i][2] + b4.z + r4.z;
        o.w = acc[i][3] + b4.w + r4.w;
        *(float4*)(outbuf + (size_t)m * HID + nb) = o;
    }
}

// ---------------- Kernel 7: head GEMM ----------------
__global__ __launch_bounds__(64) void head_kernel(
    const float* __restrict__ out, const float* __restrict__ head_w,
    const float* __restrict__ head_b, float* __restrict__ logits)
{
    __shared__ float row[HID];
    int m = blockIdx.x;
    int t = threadIdx.x;
    for (int i = t; i < HID / 4; i += 64)
        ((float4*)row)[i] = ((const float4*)(out + (size_t)m * HID))[i];
    __syncthreads();
    if (t < VOCAB) {
        float s = head_b[t];
        #pragma unroll 8
        for (int k = 0; k < HID; k++)
            s = fmaf(row[k], head_w[k * VOCAB + t], s);
        logits[m * VOCAB + t] = s;
    }
}

extern "C" void kernel_launch(void* const* d_in, const int* in_sizes, int n_in,
                              void* d_out, int out_size, void* d_ws, size_t ws_size,
                              hipStream_t stream) {
    const int*   tokens  = (const int*)d_in[0];
    const float* embed_w = (const float*)d_in[1];
    const float* norm_w  = (const float*)d_in[2];
    const float* in_w    = (const float*)d_in[3];
    const float* in_b    = (const float*)d_in[4];
    const float* out_w   = (const float*)d_in[5];
    const float* out_b   = (const float*)d_in[6];
    const float* head_w  = (const float*)d_in[7];
    const float* head_b  = (const float*)d_in[8];
    float* logits = (float*)d_out;

    float* w = (float*)d_ws;
    float* xn     = w;                                  // 4096*1024, reused as out
    float* a_buf  = xn + (size_t)MTOK * HID;            // 4096*4096, reused as y
    float* bx_buf = a_buf + (size_t)MTOK * STT;
    float* c_buf  = bx_buf + (size_t)MTOK * STT;
    float* chunkA = c_buf + (size_t)MTOK * STT;         // 8192*32
    float* chunkH = chunkA + 8192 * NCHUNK;
    float* carry  = chunkH + 8192 * NCHUNK;

    hipLaunchKernelGGL(embed_norm_kernel, dim3(MTOK), dim3(256), 0, stream,
                       tokens, embed_w, norm_w, xn);
    hipLaunchKernelGGL(gemm_in_kernel, dim3(STT / BN, MTOK / BM), dim3(256), 0, stream,
                       xn, in_w, in_b, a_buf, bx_buf, c_buf);
    hipLaunchKernelGGL(scan_phase1, dim3(1024), dim3(256), 0, stream,
                       a_buf, bx_buf, chunkA, chunkH);
    hipLaunchKernelGGL(scan_phase2, dim3(32), dim3(256), 0, stream,
                       chunkA, chunkH, carry);
    hipLaunchKernelGGL(scan_phase3, dim3(1024), dim3(256), 0, stream,
                       a_buf, bx_buf, c_buf, carry);
    hipLaunchKernelGGL(gemm_out_kernel, dim3(HID / BN, MTOK / BM), dim3(256), 0, stream,
                       a_buf, out_w, out_b, tokens, embed_w, xn);
    hipLaunchKernelGGL(head_kernel, dim3(MTOK), dim3(64), 0, stream,
                       xn, head_w, head_b, logits);
}

// Round 2
// 415.372 us; speedup vs baseline: 5.0421x; 5.0421x over previous
//
#include <hip/hip_runtime.h>
#include <math.h>

#define HID   1024
#define STT   4096
#define MTOK  4096   // B*L
#define LSEQ  2048
#define NCHUNK 32
#define CHUNK  64
#define VOCAB  62

typedef __attribute__((ext_vector_type(8))) short short8v;
typedef __attribute__((ext_vector_type(4))) float float4v;

typedef const __attribute__((address_space(1))) void* gptr_t;
typedef __attribute__((address_space(3))) void* lptr_t;

__device__ __forceinline__ float sigmoidf_(float x) {
    return 1.0f / (1.0f + expf(-x));
}
__device__ __forceinline__ unsigned short f2bf(float f) {
    unsigned int u = __float_as_uint(f);
    unsigned int r = (u + 0x7fffu + ((u >> 16) & 1u)) >> 16;
    return (unsigned short)r;
}
__device__ __forceinline__ float bf2f(unsigned short b) {
    return __uint_as_float(((unsigned int)b) << 16);
}

// ---------------- cast + transpose: src[R][C] f32 -> dst[C][R] bf16 ----------
__global__ __launch_bounds__(256) void cast_transpose_kernel(
    const float* __restrict__ src, unsigned short* __restrict__ dst, int R, int C)
{
    __shared__ float tile[32][33];
    int c0 = blockIdx.x * 32, r0 = blockIdx.y * 32;
    int t = threadIdx.x;
    int r = t >> 3, c4 = (t & 7) << 2;
    float4 v = *(const float4*)(src + (size_t)(r0 + r) * C + c0 + c4);
    tile[r][c4 + 0] = v.x; tile[r][c4 + 1] = v.y;
    tile[r][c4 + 2] = v.z; tile[r][c4 + 3] = v.w;
    __syncthreads();
    int oc = t >> 3;          // tile-local dst row (orig col)
    int orr = (t & 7) << 2;   // orig rows, 4 consecutive
    ushort4 o;
    o.x = f2bf(tile[orr + 0][oc]); o.y = f2bf(tile[orr + 1][oc]);
    o.z = f2bf(tile[orr + 2][oc]); o.w = f2bf(tile[orr + 3][oc]);
    *(ushort4*)(dst + (size_t)(c0 + oc) * R + r0 + orr) = o;
}

// ---------------- embedding gather + RMSNorm -> bf16 ----------------
__global__ __launch_bounds__(256) void embed_norm_kernel(
    const int* __restrict__ tokens, const float* __restrict__ embed_w,
    const float* __restrict__ norm_w, unsigned short* __restrict__ xn)
{
    int m = blockIdx.x;
    int t = threadIdx.x;
    int tok = tokens[m];
    float4 x = ((const float4*)(embed_w + (size_t)tok * HID))[t];
    float ss = x.x * x.x + x.y * x.y + x.z * x.z + x.w * x.w;
    for (int off = 32; off > 0; off >>= 1) ss += __shfl_down(ss, off);
    __shared__ float wsum[4];
    if ((t & 63) == 0) wsum[t >> 6] = ss;
    __syncthreads();
    float tot = wsum[0] + wsum[1] + wsum[2] + wsum[3];
    float scale = rsqrtf(tot / (float)HID + 1e-6f);
    float4 w4 = ((const float4*)norm_w)[t];
    ushort4 o;
    o.x = f2bf(x.x * scale * w4.x); o.y = f2bf(x.y * scale * w4.y);
    o.z = f2bf(x.z * scale * w4.z); o.w = f2bf(x.w * scale * w4.w);
    *(ushort4*)(xn + (size_t)m * HID + (t << 2)) = o;
}

// ---------------- MFMA GEMM 1: proj = xn @ in_w + in_b  (bf16 out) ----------
// A: xn bf16 [MTOK][1024]; B: in_wT bf16 [16384][1024]; C: proj bf16 [MTOK][16384]
__global__ __launch_bounds__(256) void gemm_in_mfma(
    const unsigned short* __restrict__ A, const unsigned short* __restrict__ B,
    const float* __restrict__ bias, unsigned short* __restrict__ Cout)
{
    __shared__ __align__(16) unsigned short As[128 * 32];
    __shared__ __align__(16) unsigned short Bs[128 * 32];
    int tid = threadIdx.x;
    int wid = tid >> 6, lane = tid & 63;
    int m0 = blockIdx.y * 128, n0 = blockIdx.x * 128;
    int wm = wid >> 1, wn = wid & 1;
    int lr = lane & 15, lk = lane >> 4;

    float4v acc[4][4];
    float4v z = {0.f, 0.f, 0.f, 0.f};
    #pragma unroll
    for (int i = 0; i < 4; i++)
        #pragma unroll
        for (int j = 0; j < 4; j++) acc[i][j] = z;

    for (int kt = 0; kt < 1024; kt += 32) {
        #pragma unroll
        for (int i = 0; i < 2; i++) {
            int c = wid * 128 + i * 64 + lane;
            int row = c >> 2, off = (c & 3) << 3;
            __builtin_amdgcn_global_load_lds(
                (gptr_t)(const void*)(A + (size_t)(m0 + row) * 1024 + kt + off),
                (lptr_t)(void*)(As + (size_t)(wid * 128 + i * 64) * 8), 16, 0, 0);
            __builtin_amdgcn_global_load_lds(
                (gptr_t)(const void*)(B + (size_t)(n0 + row) * 1024 + kt + off),
                (lptr_t)(void*)(Bs + (size_t)(wid * 128 + i * 64) * 8), 16, 0, 0);
        }
        __syncthreads();
        short8v af[4], bfr[4];
        #pragma unroll
        for (int f = 0; f < 4; f++) {
            af[f]  = *(const short8v*)&As[(wm * 64 + f * 16 + lr) * 32 + lk * 8];
            bfr[f] = *(const short8v*)&Bs[(wn * 64 + f * 16 + lr) * 32 + lk * 8];
        }
        #pragma unroll
        for (int mf = 0; mf < 4; mf++)
            #pragma unroll
            for (int nf = 0; nf < 4; nf++)
                acc[mf][nf] = __builtin_amdgcn_mfma_f32_16x16x32_bf16(
                    af[mf], bfr[nf], acc[mf][nf], 0, 0, 0);
        __syncthreads();
    }
    int rbase = lk << 2;
    #pragma unroll
    for (int mf = 0; mf < 4; mf++)
        #pragma unroll
        for (int nf = 0; nf < 4; nf++) {
            int n = n0 + wn * 64 + nf * 16 + lr;
            float bv = bias[n];
            #pragma unroll
            for (int q = 0; q < 4; q++) {
                int m = m0 + wm * 64 + mf * 16 + rbase + q;
                Cout[(size_t)m * 16384 + n] = f2bf(acc[mf][nf][q] + bv);
            }
        }
}

// ---------------- MFMA GEMM 2: out = y @ out_w + out_b + residual (f32 out) --
// A: y bf16 [MTOK][4096]; B: out_wT bf16 [1024][4096]; C: out f32 [MTOK][1024]
__global__ __launch_bounds__(256) void gemm_out_mfma(
    const unsigned short* __restrict__ A, const unsigned short* __restrict__ B,
    const float* __restrict__ out_b, const int* __restrict__ tokens,
    const float* __restrict__ embed_w, float* __restrict__ Cout)
{
    __shared__ __align__(16) unsigned short As[128 * 32];
    __shared__ __align__(16) unsigned short Bs[128 * 32];
    int tid = threadIdx.x;
    int wid = tid >> 6, lane = tid & 63;
    int m0 = blockIdx.y * 128, n0 = blockIdx.x * 128;
    int wm = wid >> 1, wn = wid & 1;
    int lr = lane & 15, lk = lane >> 4;

    float4v acc[4][4];
    float4v z = {0.f, 0.f, 0.f, 0.f};
    #pragma unroll
    for (int i = 0; i < 4; i++)
        #pragma unroll
        for (int j = 0; j < 4; j++) acc[i][j] = z;

    for (int kt = 0; kt < 4096; kt += 32) {
        #pragma unroll
        for (int i = 0; i < 2; i++) {
            int c = wid * 128 + i * 64 + lane;
            int row = c >> 2, off = (c & 3) << 3;
            __builtin_amdgcn_global_load_lds(
                (gptr_t)(const void*)(A + (size_t)(m0 + row) * 4096 + kt + off),
                (lptr_t)(void*)(As + (size_t)(wid * 128 + i * 64) * 8), 16, 0, 0);
            __builtin_amdgcn_global_load_lds(
                (gptr_t)(const void*)(B + (size_t)(n0 + row) * 4096 + kt + off),
                (lptr_t)(void*)(Bs + (size_t)(wid * 128 + i * 64) * 8), 16, 0, 0);
        }
        __syncthreads();
        short8v af[4], bfr[4];
        #pragma unroll
        for (int f = 0; f < 4; f++) {
            af[f]  = *(const short8v*)&As[(wm * 64 + f * 16 + lr) * 32 + lk * 8];
            bfr[f] = *(const short8v*)&Bs[(wn * 64 + f * 16 + lr) * 32 + lk * 8];
        }
        #pragma unroll
        for (int mf = 0; mf < 4; mf++)
            #pragma unroll
            for (int nf = 0; nf < 4; nf++)
                acc[mf][nf] = __builtin_amdgcn_mfma_f32_16x16x32_bf16(
                    af[mf], bfr[nf], acc[mf][nf], 0, 0, 0);
        __syncthreads();
    }
    int rbase = lk << 2;
    #pragma unroll
    for (int mf = 0; mf < 4; mf++) {
        #pragma unroll
        for (int q = 0; q < 4; q++) {
            int m = m0 + wm * 64 + mf * 16 + rbase + q;
            int tok = tokens[m];
            #pragma unroll
            for (int nf = 0; nf < 4; nf++) {
                int n = n0 + wn * 64 + nf * 16 + lr;
                float v = acc[mf][nf][q] + out_b[n] + embed_w[(size_t)tok * HID + n];
                Cout[(size_t)m * HID + n] = v;
            }
        }
    }
}

// ---------------- scan phase 1: per-chunk (A, H) from proj ----------------
__global__ __launch_bounds__(256) void scan_phase1(
    const unsigned short* __restrict__ proj,
    float* __restrict__ chunkA, float* __restrict__ chunkH)
{
    int bid = blockIdx.x;                  // 16 sgrp x 32 chunk x 2 batch
    int sg = bid & 15, q = (bid >> 4) & 31, b = bid >> 9;
    int s = sg * 256 + threadIdx.x;
    int t0 = q * CHUNK;
    float Aa = 1.f, Hh = 0.f;
    const unsigned short* p = proj + (size_t)(b * LSEQ + t0) * 16384 + s;
    for (int t = 0; t < CHUNK; t++) {
        float xg = bf2f(p[0]);
        float al = bf2f(p[4096]);
        float bl = bf2f(p[8192]);
        float a = sigmoidf_(al);
        float bx = sigmoidf_(bl) * xg;
        Hh = fmaf(a, Hh, bx);
        Aa *= a;
        p += 16384;
    }
    int ch = b * STT + s;
    chunkA[ch * NCHUNK + q] = Aa;
    chunkH[ch * NCHUNK + q] = Hh;
}

__global__ __launch_bounds__(256) void scan_phase2(
    const float* __restrict__ chunkA, const float* __restrict__ chunkH,
    float* __restrict__ carry)
{
    int ch = blockIdx.x * 256 + threadIdx.x;
    float c = 0.f;
    for (int q = 0; q < NCHUNK; q++) {
        carry[ch * NCHUNK + q] = c;
        c = fmaf(chunkA[ch * NCHUNK + q], c, chunkH[ch * NCHUNK + q]);
    }
}

// ---------------- scan phase 3: h with carry, y = sig(c_l)*h (bf16) --------
__global__ __launch_bounds__(256) void scan_phase3(
    const unsigned short* __restrict__ proj, const float* __restrict__ carry,
    unsigned short* __restrict__ y)
{
    int bid = blockIdx.x;
    int sg = bid & 15, q = (bid >> 4) & 31, b = bid >> 9;
    int s = sg * 256 + threadIdx.x;
    int t0 = q * CHUNK;
    int ch = b * STT + s;
    float h = carry[ch * NCHUNK + q];
    const unsigned short* p = proj + (size_t)(b * LSEQ + t0) * 16384 + s;
    unsigned short* yp = y + (size_t)(b * LSEQ + t0) * STT + s;
    for (int t = 0; t < CHUNK; t++) {
        float xg = bf2f(p[0]);
        float al = bf2f(p[4096]);
        float bl = bf2f(p[8192]);
        float cl = bf2f(p[12288]);
        float a = sigmoidf_(al);
        float bx = sigmoidf_(bl) * xg;
        h = fmaf(a, h, bx);
        *yp = f2bf(sigmoidf_(cl) * h);
        p += 16384; yp += STT;
    }
}

// ---------------- head GEMM ----------------
__global__ __launch_bounds__(64) void head_kernel(
    const float* __restrict__ out, const float* __restrict__ head_w,
    const float* __restrict__ head_b, float* __restrict__ logits)
{
    __shared__ float row[HID];
    int m = blockIdx.x;
    int t = threadIdx.x;
    for (int i = t; i < HID / 4; i += 64)
        ((float4*)row)[i] = ((const float4*)(out + (size_t)m * HID))[i];
    __syncthreads();
    if (t < VOCAB) {
        float s = head_b[t];
        #pragma unroll 8
        for (int k = 0; k < HID; k++)
            s = fmaf(row[k], head_w[k * VOCAB + t], s);
        logits[m * VOCAB + t] = s;
    }
}

extern "C" void kernel_launch(void* const* d_in, const int* in_sizes, int n_in,
                              void* d_out, int out_size, void* d_ws, size_t ws_size,
                              hipStream_t stream) {
    const int*   tokens  = (const int*)d_in[0];
    const float* embed_w = (const float*)d_in[1];
    const float* norm_w  = (const float*)d_in[2];
    const float* in_w    = (const float*)d_in[3];
    const float* in_b    = (const float*)d_in[4];
    const float* out_w   = (const float*)d_in[5];
    const float* out_b   = (const float*)d_in[6];
    const float* head_w  = (const float*)d_in[7];
    const float* head_b  = (const float*)d_in[8];
    float* logits = (float*)d_out;

    char* w = (char*)d_ws;
    unsigned short* proj   = (unsigned short*)w;                    // 128 MiB
    unsigned short* y      = (unsigned short*)(w + 134217728);      // 32 MiB
    unsigned short* in_wT  = (unsigned short*)(w + 167772160);      // 32 MiB
    float*          outbuf = (float*)(w + 167772160);               // reuses in_wT (16 MiB)
    unsigned short* xn     = (unsigned short*)(w + 201326592);      // 8 MiB
    unsigned short* out_wT = (unsigned short*)(w + 201326592);      // reuses xn (8 MiB)
    float* chunkA = (float*)(w + 209715200);
    float* chunkH = chunkA + 8192 * NCHUNK;
    float* carry  = chunkH + 8192 * NCHUNK;

    // in_w [1024][16384] -> in_wT [16384][1024] bf16
    hipLaunchKernelGGL(cast_transpose_kernel, dim3(16384 / 32, 1024 / 32), dim3(256), 0, stream,
                       in_w, in_wT, 1024, 16384);
    hipLaunchKernelGGL(embed_norm_kernel, dim3(MTOK), dim3(256), 0, stream,
                       tokens, embed_w, norm_w, xn);
    hipLaunchKernelGGL(gemm_in_mfma, dim3(16384 / 128, MTOK / 128), dim3(256), 0, stream,
                       xn, in_wT, in_b, proj);
    hipLaunchKernelGGL(scan_phase1, dim3(1024), dim3(256), 0, stream,
                       proj, chunkA, chunkH);
    hipLaunchKernelGGL(scan_phase2, dim3(32), dim3(256), 0, stream,
                       chunkA, chunkH, carry);
    hipLaunchKernelGGL(scan_phase3, dim3(1024), dim3(256), 0, stream,
                       proj, carry, y);
    // out_w [4096][1024] -> out_wT [1024][4096] bf16  (xn region is dead now)
    hipLaunchKernelGGL(cast_transpose_kernel, dim3(1024 / 32, 4096 / 32), dim3(256), 0, stream,
                       out_w, out_wT, 4096, 1024);
    hipLaunchKernelGGL(gemm_out_mfma, dim3(HID / 128, MTOK / 128), dim3(256), 0, stream,
                       y, out_wT, out_b, tokens, embed_w, outbuf);
    hipLaunchKernelGGL(head_kernel, dim3(MTOK), dim3(64), 0, stream,
                       outbuf, head_w, head_b, logits);
}

// Round 3
// 387.009 us; speedup vs baseline: 5.4116x; 1.0733x over previous
//
#include <hip/hip_runtime.h>
#include <math.h>

#define HID   1024
#define STT   4096
#define MTOK  4096   // B*L
#define LSEQ  2048
#define NCHUNK 32
#define CHUNK  64
#define VOCAB  62

typedef __attribute__((ext_vector_type(8))) short short8v;
typedef __attribute__((ext_vector_type(4))) float float4v;

typedef const __attribute__((address_space(1))) void* gptr_t;
typedef __attribute__((address_space(3))) void* lptr_t;

__device__ __forceinline__ float sigmoidf_(float x) {
    return 1.0f / (1.0f + expf(-x));
}
__device__ __forceinline__ unsigned short f2bf(float f) {
    unsigned int u = __float_as_uint(f);
    unsigned int r = (u + 0x7fffu + ((u >> 16) & 1u)) >> 16;
    return (unsigned short)r;
}
__device__ __forceinline__ float bf2f(unsigned short b) {
    return __uint_as_float(((unsigned int)b) << 16);
}

// ---------------- cast + transpose: src[R][C] f32 -> dst[C][R] bf16 ----------
__global__ __launch_bounds__(256) void cast_transpose_kernel(
    const float* __restrict__ src, unsigned short* __restrict__ dst, int R, int C)
{
    __shared__ float tile[32][33];
    int c0 = blockIdx.x * 32, r0 = blockIdx.y * 32;
    int t = threadIdx.x;
    int r = t >> 3, c4 = (t & 7) << 2;
    float4 v = *(const float4*)(src + (size_t)(r0 + r) * C + c0 + c4);
    tile[r][c4 + 0] = v.x; tile[r][c4 + 1] = v.y;
    tile[r][c4 + 2] = v.z; tile[r][c4 + 3] = v.w;
    __syncthreads();
    int oc = t >> 3;
    int orr = (t & 7) << 2;
    ushort4 o;
    o.x = f2bf(tile[orr + 0][oc]); o.y = f2bf(tile[orr + 1][oc]);
    o.z = f2bf(tile[orr + 2][oc]); o.w = f2bf(tile[orr + 3][oc]);
    *(ushort4*)(dst + (size_t)(c0 + oc) * R + r0 + orr) = o;
}

// ---------------- embedding gather + RMSNorm -> bf16 ----------------
__global__ __launch_bounds__(256) void embed_norm_kernel(
    const int* __restrict__ tokens, const float* __restrict__ embed_w,
    const float* __restrict__ norm_w, unsigned short* __restrict__ xn)
{
    int m = blockIdx.x;
    int t = threadIdx.x;
    int tok = tokens[m];
    float4 x = ((const float4*)(embed_w + (size_t)tok * HID))[t];
    float ss = x.x * x.x + x.y * x.y + x.z * x.z + x.w * x.w;
    for (int off = 32; off > 0; off >>= 1) ss += __shfl_down(ss, off);
    __shared__ float wsum[4];
    if ((t & 63) == 0) wsum[t >> 6] = ss;
    __syncthreads();
    float tot = wsum[0] + wsum[1] + wsum[2] + wsum[3];
    float scale = rsqrtf(tot / (float)HID + 1e-6f);
    float4 w4 = ((const float4*)norm_w)[t];
    ushort4 o;
    o.x = f2bf(x.x * scale * w4.x); o.y = f2bf(x.y * scale * w4.y);
    o.z = f2bf(x.z * scale * w4.z); o.w = f2bf(x.w * scale * w4.w);
    *(ushort4*)(xn + (size_t)m * HID + (t << 2)) = o;
}

// ---------------- MFMA GEMM 1: proj = xn @ in_w + in_b  (bf16 out) ----------
// 256x256 tile, BK=32, 8 waves (2M x 4N), 4-buffer depth-3 counted-vmcnt pipeline.
// A: xn bf16 [4096][1024]; B: in_wT bf16 [16384][1024]; C: proj bf16 [4096][16384]
__global__ __launch_bounds__(512, 2) void gemm_in_mfma(
    const unsigned short* __restrict__ A, const unsigned short* __restrict__ B,
    const float* __restrict__ bias, unsigned short* __restrict__ Cout)
{
    extern __shared__ unsigned short lds[];   // 4 bufs * (8192 A + 8192 B) = 128 KiB
    int tid = threadIdx.x;
    int wid = tid >> 6, lane = tid & 63;
    // XCD-aware swizzle (nwg = 1024, divisible by 8 -> simple form bijective)
    int wg = blockIdx.x;
    int swz = (wg & 7) * 128 + (wg >> 3);
    int bx = swz & 63;          // n-tile (64 tiles)
    int by = swz >> 6;          // m-tile (16 tiles)
    int m0 = by * 256, n0 = bx * 256;
    int wm = wid >> 2, wn = wid & 3;
    int lr = lane & 15, lk = lane >> 4;

    auto stage = [&](int b, int kt) {
        unsigned short* As = lds + b * 16384;
        unsigned short* Bs = As + 8192;
        #pragma unroll
        for (int i = 0; i < 2; i++) {
            int ch = i * 512 + wid * 64 + lane;
            int row = ch >> 2, off = (ch & 3) << 3;
            __builtin_amdgcn_global_load_lds(
                (gptr_t)(const void*)(A + (size_t)(m0 + row) * 1024 + kt + off),
                (lptr_t)(void*)(As + (size_t)(i * 512 + wid * 64) * 8), 16, 0, 0);
            __builtin_amdgcn_global_load_lds(
                (gptr_t)(const void*)(B + (size_t)(n0 + row) * 1024 + kt + off),
                (lptr_t)(void*)(Bs + (size_t)(i * 512 + wid * 64) * 8), 16, 0, 0);
        }
    };

    float4v acc[8][4];
    float4v z = {0.f, 0.f, 0.f, 0.f};
    #pragma unroll
    for (int i = 0; i < 8; i++)
        #pragma unroll
        for (int j = 0; j < 4; j++) acc[i][j] = z;

    const int nt = 1024 / 32;
    stage(0, 0); stage(1, 32); stage(2, 64);

    for (int t = 0; t < nt; ++t) {
        if (t + 3 < nt) stage((t + 3) & 3, (t + 3) * 32);
        if (t + 3 < nt)      asm volatile("s_waitcnt vmcnt(12)" ::: "memory");
        else if (t + 2 < nt) asm volatile("s_waitcnt vmcnt(8)" ::: "memory");
        else if (t + 1 < nt) asm volatile("s_waitcnt vmcnt(4)" ::: "memory");
        else                 asm volatile("s_waitcnt vmcnt(0)" ::: "memory");
        __builtin_amdgcn_s_barrier();
        asm volatile("" ::: "memory");
        const unsigned short* As = lds + (t & 3) * 16384;
        const unsigned short* Bs = As + 8192;
        short8v af[8], bfr[4];
        #pragma unroll
        for (int mf = 0; mf < 8; mf++)
            af[mf] = *(const short8v*)&As[(wm * 128 + mf * 16 + lr) * 32 + lk * 8];
        #pragma unroll
        for (int nf = 0; nf < 4; nf++)
            bfr[nf] = *(const short8v*)&Bs[(wn * 64 + nf * 16 + lr) * 32 + lk * 8];
        __builtin_amdgcn_s_setprio(1);
        #pragma unroll
        for (int mf = 0; mf < 8; mf++)
            #pragma unroll
            for (int nf = 0; nf < 4; nf++)
                acc[mf][nf] = __builtin_amdgcn_mfma_f32_16x16x32_bf16(
                    af[mf], bfr[nf], acc[mf][nf], 0, 0, 0);
        __builtin_amdgcn_s_setprio(0);
        asm volatile("" ::: "memory");
        __builtin_amdgcn_s_barrier();
    }

    int rbase = lk << 2;
    #pragma unroll
    for (int mf = 0; mf < 8; mf++)
        #pragma unroll
        for (int nf = 0; nf < 4; nf++) {
            int n = n0 + wn * 64 + nf * 16 + lr;
            float bv = bias[n];
            #pragma unroll
            for (int q = 0; q < 4; q++) {
                int m = m0 + wm * 128 + mf * 16 + rbase + q;
                Cout[(size_t)m * 16384 + n] = f2bf(acc[mf][nf][q] + bv);
            }
        }
}

// ---------------- MFMA GEMM 2: out = y @ out_w + out_b + residual (f32 out) --
// 128x128 tile, BK=32, 4 waves (2x2), 3-buffer depth-2 counted-vmcnt pipeline.
// A: y bf16 [4096][4096]; B: out_wT bf16 [1024][4096]; C: out f32 [4096][1024]
__global__ __launch_bounds__(256, 3) void gemm_out_mfma(
    const unsigned short* __restrict__ A, const unsigned short* __restrict__ B,
    const float* __restrict__ out_b, const int* __restrict__ tokens,
    const float* __restrict__ embed_w, float* __restrict__ Cout)
{
    extern __shared__ unsigned short lds[];   // 3 bufs * (4096 A + 4096 B) = 48 KiB
    int tid = threadIdx.x;
    int wid = tid >> 6, lane = tid & 63;
    int wg = blockIdx.x;                      // 256 WGs: 8 n-tiles x 32 m-tiles
    int swz = (wg & 7) * 32 + (wg >> 3);
    int bx = swz & 7;
    int by = swz >> 3;
    int m0 = by * 128, n0 = bx * 128;
    int wm = wid >> 1, wn = wid & 1;
    int lr = lane & 15, lk = lane >> 4;

    auto stage = [&](int b, int kt) {
        unsigned short* As = lds + b * 8192;
        unsigned short* Bs = As + 4096;
        #pragma unroll
        for (int i = 0; i < 2; i++) {
            int ch = i * 256 + wid * 64 + lane;
            int row = ch >> 2, off = (ch & 3) << 3;
            __builtin_amdgcn_global_load_lds(
                (gptr_t)(const void*)(A + (size_t)(m0 + row) * 4096 + kt + off),
                (lptr_t)(void*)(As + (size_t)(i * 256 + wid * 64) * 8), 16, 0, 0);
            __builtin_amdgcn_global_load_lds(
                (gptr_t)(const void*)(B + (size_t)(n0 + row) * 4096 + kt + off),
                (lptr_t)(void*)(Bs + (size_t)(i * 256 + wid * 64) * 8), 16, 0, 0);
        }
    };

    float4v acc[4][4];
    float4v z = {0.f, 0.f, 0.f, 0.f};
    #pragma unroll
    for (int i = 0; i < 4; i++)
        #pragma unroll
        for (int j = 0; j < 4; j++) acc[i][j] = z;

    const int nt = 4096 / 32;
    stage(0, 0); stage(1, 32);

    for (int t = 0; t < nt; ++t) {
        if (t + 2 < nt) stage((t + 2) % 3, (t + 2) * 32);
        if (t + 2 < nt)      asm volatile("s_waitcnt vmcnt(8)" ::: "memory");
        else if (t + 1 < nt) asm volatile("s_waitcnt vmcnt(4)" ::: "memory");
        else                 asm volatile("s_waitcnt vmcnt(0)" ::: "memory");
        __builtin_amdgcn_s_barrier();
        asm volatile("" ::: "memory");
        const unsigned short* As = lds + (t % 3) * 8192;
        const unsigned short* Bs = As + 4096;
        short8v af[4], bfr[4];
        #pragma unroll
        for (int f = 0; f < 4; f++) {
            af[f]  = *(const short8v*)&As[(wm * 64 + f * 16 + lr) * 32 + lk * 8];
            bfr[f] = *(const short8v*)&Bs[(wn * 64 + f * 16 + lr) * 32 + lk * 8];
        }
        __builtin_amdgcn_s_setprio(1);
        #pragma unroll
        for (int mf = 0; mf < 4; mf++)
            #pragma unroll
            for (int nf = 0; nf < 4; nf++)
                acc[mf][nf] = __builtin_amdgcn_mfma_f32_16x16x32_bf16(
                    af[mf], bfr[nf], acc[mf][nf], 0, 0, 0);
        __builtin_amdgcn_s_setprio(0);
        asm volatile("" ::: "memory");
        __builtin_amdgcn_s_barrier();
    }

    int rbase = lk << 2;
    #pragma unroll
    for (int mf = 0; mf < 4; mf++) {
        #pragma unroll
        for (int q = 0; q < 4; q++) {
            int m = m0 + wm * 64 + mf * 16 + rbase + q;
            int tok = tokens[m];
            #pragma unroll
            for (int nf = 0; nf < 4; nf++) {
                int n = n0 + wn * 64 + nf * 16 + lr;
                float v = acc[mf][nf][q] + out_b[n] + embed_w[(size_t)tok * HID + n];
                Cout[(size_t)m * HID + n] = v;
            }
        }
    }
}

// ---------------- scan phase 1: per-chunk (A, H) from proj ----------------
__global__ __launch_bounds__(256) void scan_phase1(
    const unsigned short* __restrict__ proj,
    float* __restrict__ chunkA, float* __restrict__ chunkH)
{
    int bid = blockIdx.x;
    int sg = bid & 15, q = (bid >> 4) & 31, b = bid >> 9;
    int s = sg * 256 + threadIdx.x;
    int t0 = q * CHUNK;
    float Aa = 1.f, Hh = 0.f;
    const unsigned short* p = proj + (size_t)(b * LSEQ + t0) * 16384 + s;
    for (int t = 0; t < CHUNK; t++) {
        float xg = bf2f(p[0]);
        float al = bf2f(p[4096]);
        float bl = bf2f(p[8192]);
        float a = sigmoidf_(al);
        float bx = sigmoidf_(bl) * xg;
        Hh = fmaf(a, Hh, bx);
        Aa *= a;
        p += 16384;
    }
    int ch = b * STT + s;
    chunkA[ch * NCHUNK + q] = Aa;
    chunkH[ch * NCHUNK + q] = Hh;
}

__global__ __launch_bounds__(256) void scan_phase2(
    const float* __restrict__ chunkA, const float* __restrict__ chunkH,
    float* __restrict__ carry)
{
    int ch = blockIdx.x * 256 + threadIdx.x;
    float c = 0.f;
    for (int q = 0; q < NCHUNK; q++) {
        carry[ch * NCHUNK + q] = c;
        c = fmaf(chunkA[ch * NCHUNK + q], c, chunkH[ch * NCHUNK + q]);
    }
}

// ---------------- scan phase 3: h with carry, y = sig(c_l)*h (bf16) --------
__global__ __launch_bounds__(256) void scan_phase3(
    const unsigned short* __restrict__ proj, const float* __restrict__ carry,
    unsigned short* __restrict__ y)
{
    int bid = blockIdx.x;
    int sg = bid & 15, q = (bid >> 4) & 31, b = bid >> 9;
    int s = sg * 256 + threadIdx.x;
    int t0 = q * CHUNK;
    int ch = b * STT + s;
    float h = carry[ch * NCHUNK + q];
    const unsigned short* p = proj + (size_t)(b * LSEQ + t0) * 16384 + s;
    unsigned short* yp = y + (size_t)(b * LSEQ + t0) * STT + s;
    for (int t = 0; t < CHUNK; t++) {
        float xg = bf2f(p[0]);
        float al = bf2f(p[4096]);
        float bl = bf2f(p[8192]);
        float cl = bf2f(p[12288]);
        float a = sigmoidf_(al);
        float bx = sigmoidf_(bl) * xg;
        h = fmaf(a, h, bx);
        *yp = f2bf(sigmoidf_(cl) * h);
        p += 16384; yp += STT;
    }
}

// ---------------- head GEMM ----------------
__global__ __launch_bounds__(64) void head_kernel(
    const float* __restrict__ out, const float* __restrict__ head_w,
    const float* __restrict__ head_b, float* __restrict__ logits)
{
    __shared__ float row[HID];
    int m = blockIdx.x;
    int t = threadIdx.x;
    for (int i = t; i < HID / 4; i += 64)
        ((float4*)row)[i] = ((const float4*)(out + (size_t)m * HID))[i];
    __syncthreads();
    if (t < VOCAB) {
        float s = head_b[t];
        #pragma unroll 8
        for (int k = 0; k < HID; k++)
            s = fmaf(row[k], head_w[k * VOCAB + t], s);
        logits[m * VOCAB + t] = s;
    }
}

extern "C" void kernel_launch(void* const* d_in, const int* in_sizes, int n_in,
                              void* d_out, int out_size, void* d_ws, size_t ws_size,
                              hipStream_t stream) {
    const int*   tokens  = (const int*)d_in[0];
    const float* embed_w = (const float*)d_in[1];
    const float* norm_w  = (const float*)d_in[2];
    const float* in_w    = (const float*)d_in[3];
    const float* in_b    = (const float*)d_in[4];
    const float* out_w   = (const float*)d_in[5];
    const float* out_b   = (const float*)d_in[6];
    const float* head_w  = (const float*)d_in[7];
    const float* head_b  = (const float*)d_in[8];
    float* logits = (float*)d_out;

    char* w = (char*)d_ws;
    unsigned short* proj   = (unsigned short*)w;                    // 128 MiB
    unsigned short* y      = (unsigned short*)(w + 134217728);      // 32 MiB
    unsigned short* in_wT  = (unsigned short*)(w + 167772160);      // 32 MiB
    float*          outbuf = (float*)(w + 167772160);               // reuses in_wT (16 MiB)
    unsigned short* xn     = (unsigned short*)(w + 201326592);      // 8 MiB
    unsigned short* out_wT = (unsigned short*)(w + 201326592);      // reuses xn (8 MiB)
    float* chunkA = (float*)(w + 209715200);
    float* chunkH = chunkA + 8192 * NCHUNK;
    float* carry  = chunkH + 8192 * NCHUNK;

    hipLaunchKernelGGL(cast_transpose_kernel, dim3(16384 / 32, 1024 / 32), dim3(256), 0, stream,
                       in_w, in_wT, 1024, 16384);
    hipLaunchKernelGGL(embed_norm_kernel, dim3(MTOK), dim3(256), 0, stream,
                       tokens, embed_w, norm_w, xn);
    hipLaunchKernelGGL(gemm_in_mfma, dim3(1024), dim3(512), 131072, stream,
                       xn, in_wT, in_b, proj);
    hipLaunchKernelGGL(scan_phase1, dim3(1024), dim3(256), 0, stream,
                       proj, chunkA, chunkH);
    hipLaunchKernelGGL(scan_phase2, dim3(32), dim3(256), 0, stream,
                       chunkA, chunkH, carry);
    hipLaunchKernelGGL(scan_phase3, dim3(1024), dim3(256), 0, stream,
                       proj, carry, y);
    hipLaunchKernelGGL(cast_transpose_kernel, dim3(1024 / 32, 4096 / 32), dim3(256), 0, stream,
                       out_w, out_wT, 4096, 1024);
    hipLaunchKernelGGL(gemm_out_mfma, dim3(256), dim3(256), 49152, stream,
                       y, out_wT, out_b, tokens, embed_w, outbuf);
    hipLaunchKernelGGL(head_kernel, dim3(MTOK), dim3(64), 0, stream,
                       outbuf, head_w, head_b, logits);
}